// Round 11
// baseline (409.505 us; speedup 1.0000x reference)
//
#include <hip/hip_runtime.h>
#include <float.h>
#include <math.h>

typedef __attribute__((ext_vector_type(8))) short bf16x8;
typedef __attribute__((ext_vector_type(4))) float f32x4;

// d_out float offsets (loss, quantized, perplexity, embedding, indices, encodings)
#define O_Q    1
#define O_PERP 8388609
#define O_EMB  8388610
#define O_IDX  9437186
#define O_ENC  9469954

// workspace float offsets: ETpk hi-limb image at byte 0 (2 MB)
#define W_CB   1048576
#define W_CNT  1052672
#define W_BS   1056768

#define MARGIN 0.4f

__device__ __forceinline__ unsigned short bf16_rne(float x) {
    unsigned u = __float_as_uint(x);
    unsigned r = u + 0x7FFFu + ((u >> 16) & 1u);
    return (unsigned short)(r >> 16);
}

__device__ __forceinline__ unsigned long long u64min(unsigned long long a, unsigned long long b){ return a < b ? a : b; }

__device__ __forceinline__ unsigned long long packkey(float s, int k) {
    unsigned u = __float_as_uint(s);
    u = (u & 0x80000000u) ? ~u : (u | 0x80000000u);
    return ((unsigned long long)u << 32) | (unsigned)k;
}
__device__ __forceinline__ float unpackf(unsigned long long key) {
    unsigned u = (unsigned)(key >> 32);
    u = (u & 0x80000000u) ? (u & 0x7FFFFFFFu) : ~u;
    return __uint_as_float(u);
}

// ---- E -> hi-limb image. chunk(kt,ks) 16KB = [codefrag16][64 units x 16B]
// unit = (kchunk*16 + coderow); lane l reads cf*1024 + l*16 -- coalesced 1KB.
__global__ __launch_bounds__(256)
void k_prepE(const float* __restrict__ E, char* __restrict__ ETpk)
{
    int gid = blockIdx.x * 256 + threadIdx.x;   // 131072 = 4096 codes * 32 octets
    int code = gid >> 5, oct = gid & 31;
    const float* ep = E + (size_t)code * 256 + oct * 8;
    float4 a = *(const float4*)ep, c4 = *(const float4*)(ep + 4);
    float v[8] = {a.x, a.y, a.z, a.w, c4.x, c4.y, c4.z, c4.w};
    unsigned hw[8];
#pragma unroll
    for (int i = 0; i < 8; ++i) hw[i] = bf16_rne(v[i]);
    uint4 vh = {hw[0]|(hw[1]<<16), hw[2]|(hw[3]<<16), hw[4]|(hw[5]<<16), hw[6]|(hw[7]<<16)};
    int kt = code >> 8, cf = (code >> 4) & 15, row = code & 15;
    int dtv = oct >> 2, c = oct & 3;
    size_t chunk = (size_t)(kt * 8 + dtv) * 16384;
    *(uint4*)(ETpk + chunk + (size_t)(cf * 64 + (c*16 + row)) * 16) = vh;
}

// ---- 0.5*||e_k||^2 (fp32)
__global__ __launch_bounds__(256)
void k_cbias(const float* __restrict__ E, float* __restrict__ cb)
{
    const int tid = threadIdx.x;
    const int k   = blockIdx.x * 16 + (tid >> 4);
    const int ch  = tid & 15;
    const float* p = E + (size_t)k * 256 + ch * 16;
    float s = 0.f;
#pragma unroll
    for (int i = 0; i < 4; ++i) {
        float4 v = *(const float4*)(p + i * 4);
        s += v.x*v.x + v.y*v.y + v.z*v.z + v.w*v.w;
    }
#pragma unroll
    for (int m = 1; m < 16; m <<= 1) s += __shfl_xor(s, m, 64);
    if (ch == 0) cb[k] = 0.5f * s;
}

// ---- main: fully-register 2-combo (hh+lh) limb MFMA, NO main-loop LDS/barriers.
// grid 2048, block 256 (4 waves), tile 16 tok; wave = 64 codes (wn) x 16 tok.
// A frags 64 VGPR (8 ks x 2 limbs); B streamed global->reg, even/odd dbuf.
// Per rd/wave: 4 global_load_dwordx4 (B, next rd) + 1 float2 store + 8 MFMA.
__global__ __launch_bounds__(256, 3)
void k_main(const float* __restrict__ X, const char* __restrict__ ETpk,
            const float* __restrict__ cbh, const float* __restrict__ E,
            float* __restrict__ out, int* __restrict__ counts,
            float* __restrict__ bscore)
{
    __shared__ ulonglong2 scr[1024];    // 16 tok x 64 cols (epilogue only)
    __shared__ int ids[16];
    __shared__ float wp[4];

    const int tid  = threadIdx.x;
    const int lane = tid & 63;
    const int wn   = tid >> 6;          // 0..3 code quarter (64 codes)
    const int n0   = blockIdx.x * 16;
    const int b    = n0 >> 10;
    const int l0   = n0 & 1023;
    const size_t xbase = (size_t)b * 262144 + l0;
    float* encB = out + (size_t)O_ENC + (size_t)n0 * 4096;   // even: float2 ok

    f32x4 acc[4];
#pragma unroll
    for (int nj = 0; nj < 4; ++nj) acc[nj] = (f32x4){0.f,0.f,0.f,0.f};

    float s1[4], s2v[4];
    unsigned ipack[4];
#pragma unroll
    for (int s = 0; s < 4; ++s) { s1[s] = FLT_MAX; s2v[s] = FLT_MAX; ipack[s] = 0; }

    // ---- A fragments in registers (split once)
    bf16x8 ahf[8], alf[8];
    {
        const int t_l = lane & 15;                 // token row
        const int c_l = lane >> 4;                 // k-chunk 0..3
        const float* xp = X + xbase + t_l;
#pragma unroll
        for (int ks = 0; ks < 8; ++ks) {
            const int d0 = ks * 32 + c_l * 8;
            float v[8];
#pragma unroll
            for (int i = 0; i < 8; ++i) v[i] = xp[(size_t)(d0 + i) * 1024];
            unsigned hw[8], lw[8];
#pragma unroll
            for (int i = 0; i < 8; ++i) {
                unsigned short h = bf16_rne(v[i]);
                float hf = __uint_as_float((unsigned)h << 16);
                hw[i] = h; lw[i] = bf16_rne(v[i] - hf);
            }
            uint4 vh = {hw[0]|(hw[1]<<16), hw[2]|(hw[3]<<16), hw[4]|(hw[5]<<16), hw[6]|(hw[7]<<16)};
            uint4 vl = {lw[0]|(lw[1]<<16), lw[2]|(lw[3]<<16), lw[4]|(lw[5]<<16), lw[6]|(lw[7]<<16)};
            ahf[ks] = *(bf16x8*)&vh;
            alf[ks] = *(bf16x8*)&vl;
        }
    }

    // ---- B streaming: per-lane source address (coalesced 1KB per load instr)
    const char* bsrc = ETpk + wn * 4096 + (size_t)lane * 16;
    bf16x8 bE[4], bO[4];
#pragma unroll
    for (int nj = 0; nj < 4; ++nj)
        bE[nj] = *(const bf16x8*)(bsrc + nj * 1024);   // rd 0

    // ---- main loop: 16 kt x 8 ks, no barriers, no LDS
#pragma unroll 1
    for (int kt = 0; kt < 16; ++kt) {
#pragma unroll
        for (int ks = 0; ks < 8; ++ks) {
            const int rd = kt * 8 + ks;
            const int nx = (rd + 1 < 128) ? rd + 1 : 127;
            const char* nsrc = bsrc + (size_t)nx * 16384;
            if ((ks & 1) == 0) {
#pragma unroll
                for (int nj = 0; nj < 4; ++nj)
                    bO[nj] = *(const bf16x8*)(nsrc + nj * 1024);
            } else {
#pragma unroll
                for (int nj = 0; nj < 4; ++nj)
                    bE[nj] = *(const bf16x8*)(nsrc + nj * 1024);
            }
            // zero-fill 2KB of this block's one-hot region
            *(float2*)(encB + (size_t)rd * 512 + tid * 2) = make_float2(0.f, 0.f);
            if ((ks & 1) == 0) {
#pragma unroll
                for (int nj = 0; nj < 4; ++nj) {
                    acc[nj] = __builtin_amdgcn_mfma_f32_16x16x32_bf16(ahf[ks], bE[nj], acc[nj], 0, 0, 0);
                    acc[nj] = __builtin_amdgcn_mfma_f32_16x16x32_bf16(alf[ks], bE[nj], acc[nj], 0, 0, 0);
                }
            } else {
#pragma unroll
                for (int nj = 0; nj < 4; ++nj) {
                    acc[nj] = __builtin_amdgcn_mfma_f32_16x16x32_bf16(ahf[ks], bO[nj], acc[nj], 0, 0, 0);
                    acc[nj] = __builtin_amdgcn_mfma_f32_16x16x32_bf16(alf[ks], bO[nj], acc[nj], 0, 0, 0);
                }
            }
        }
        // per-kt score + per-lane top2 (code = kt*256 + wn*64 + nj*16 + (lane&15))
        {
            const int cb0 = kt * 256 + wn * 64 + (lane & 15);
            float cbv[4];
#pragma unroll
            for (int nj = 0; nj < 4; ++nj) cbv[nj] = cbh[cb0 + nj * 16];
#pragma unroll
            for (int q = 0; q < 4; ++q)
#pragma unroll
                for (int nj = 0; nj < 4; ++nj) {
                    float s = cbv[nj] - acc[nj][q];
                    unsigned code = (unsigned)(cb0 + nj * 16);
                    if (s < s1[q]) {
                        s2v[q] = s1[q];
                        ipack[q] = ((ipack[q] & 0xFFFFu) << 16) | code;
                        s1[q] = s;
                    } else if (s < s2v[q]) {
                        s2v[q] = s;
                        ipack[q] = (ipack[q] & 0xFFFFu) | (code << 16);
                    }
                    acc[nj][q] = 0.f;
                }
        }
    }

    // drain all zero-fill stores (one-hot ordering), then epilogue LDS use
    asm volatile("s_waitcnt vmcnt(0)" ::: "memory");
    __syncthreads();

    // ---- dump per-lane top2 keys: scr[t*64 + col]
    {
        const int col = wn * 16 + (lane & 15);
#pragma unroll
        for (int q = 0; q < 4; ++q) {
            const int t = ((lane >> 4) << 2) + q;
            ulonglong2 kk;
            kk.x = packkey(s1[q],  (int)(ipack[q] & 0xFFFFu));
            kk.y = packkey(s2v[q], (int)(ipack[q] >> 16));
            scr[t * 64 + col] = kk;
        }
    }
    __syncthreads();

    // ---- per-token pool scan + conditional exact rescore
    if (tid < 16) {
        const ulonglong2* row = scr + tid * 64;
        unsigned long long m = 0xFFFFFFFFFFFFFFFFull;
#pragma unroll 1
        for (int i0 = 0; i0 < 64; ++i0) {
            int i = (4 * tid + i0) & 63;        // staggered start
            m = u64min(m, row[i].x);            // key2 >= key1 always
        }
        int k = (int)(m & 0xFFFFull);
        const float thr = unpackf(m) + MARGIN;
        int cnt = 0;
#pragma unroll 1
        for (int i0 = 0; i0 < 64; ++i0) {
            int i = (4 * tid + i0) & 63;
            ulonglong2 kk = row[i];
            cnt += (unpackf(kk.x) <= thr) + (unpackf(kk.y) <= thr);
        }
        if (cnt > 1) {
            float bd = FLT_MAX; int bi = 0x7FFFFFFF;
#pragma unroll 1
            for (int i0 = 0; i0 < 64; ++i0) {
                int i = (4 * tid + i0) & 63;
                ulonglong2 kk = row[i];
#pragma unroll
                for (int h = 0; h < 2; ++h) {
                    unsigned long long key = h ? kk.y : kk.x;
                    if (unpackf(key) <= thr) {
                        int c = (int)(key & 0xFFFFull);
                        float d = 0.f;
                        for (int dd = 0; dd < 256; dd += 2) {
                            float xv0 = X[xbase + (size_t)dd * 1024 + tid];
                            float xv1 = X[xbase + (size_t)(dd + 1) * 1024 + tid];
                            float e0 = E[(size_t)c * 256 + dd];
                            float e1 = E[(size_t)c * 256 + dd + 1];
                            float f0 = xv0 - e0, f1 = xv1 - e1;
                            d += f0 * f0 + f1 * f1;
                        }
                        if (d < bd || (d == bd && c < bi)) { bd = d; bi = c; }
                    }
                }
            }
            k = bi;
        }
        ids[tid] = k;
        out[(size_t)O_IDX + n0 + tid] = (float)k;
        atomicAdd(&counts[k], 1);
        out[(size_t)O_ENC + (size_t)(n0 + tid) * 4096 + k] = 1.0f;
    }
    __syncthreads();

    // ---- fused quantize (STE arithmetic) + exact fp32 loss partial
    float dl = 0.f;
#pragma unroll 4
    for (int r = 0; r < 16; ++r) {
        int lin = r * 256 + tid;
        int d = lin >> 4, t = lin & 15;
        float q  = E[(size_t)ids[t] * 256 + d];
        float xv = X[xbase + (size_t)d * 1024 + t];
        out[(size_t)O_Q + xbase + (size_t)d * 1024 + t] = xv + (q - xv);
        float df = q - xv;
        dl += df * df;
    }
#pragma unroll
    for (int m = 1; m < 64; m <<= 1) dl += __shfl_xor(dl, m, 64);
    if (lane == 0) wp[tid >> 6] = dl;
    __syncthreads();
    if (tid == 0)
        bscore[blockIdx.x] = wp[0] + wp[1] + wp[2] + wp[3];
}

// ---- scalars: loss + perplexity (2048 block partials)
__global__ __launch_bounds__(256)
void k_final(const float* __restrict__ bscore, const int* __restrict__ counts,
             float* __restrict__ out)
{
    const int tid = threadIdx.x;
    float s = 0.f;
#pragma unroll
    for (int i = 0; i < 8; ++i) s += bscore[tid + i * 256];
    float h = 0.f;
#pragma unroll
    for (int i = 0; i < 16; ++i) {
        float p = (float)counts[tid * 16 + i] * (1.0f / 32768.f);
        h += p * logf(p + 1e-10f);
    }
#pragma unroll
    for (int m = 1; m < 64; m <<= 1) {
        s += __shfl_xor(s, m, 64);
        h += __shfl_xor(h, m, 64);
    }
    __shared__ float rs[4], rh[4];
    if ((tid & 63) == 0) { rs[tid >> 6] = s; rh[tid >> 6] = h; }
    __syncthreads();
    if (tid == 0) {
        float S = rs[0] + rs[1] + rs[2] + rs[3];
        float H = rh[0] + rh[1] + rh[2] + rh[3];
        out[0]      = 0.25f * S / 8388608.f;
        out[O_PERP] = expf(-H);
    }
}

extern "C" void kernel_launch(void* const* d_in, const int* in_sizes, int n_in,
                              void* d_out, int out_size, void* d_ws, size_t ws_size,
                              hipStream_t stream)
{
    (void)in_sizes; (void)n_in; (void)out_size; (void)ws_size;
    const float* X = (const float*)d_in[0];
    const float* E = (const float*)d_in[1];
    float* out = (float*)d_out;
    float* ws  = (float*)d_ws;
    char*  ETpk   = (char*)ws;
    float* cbh    = ws + W_CB;
    int*   counts = (int*)(ws + W_CNT);
    float* bsc    = ws + W_BS;

    hipMemsetAsync(counts, 0, 4096 * sizeof(int), stream);
    k_prepE<<<512, 256, 0, stream>>>(E, ETpk);
    k_cbias<<<256, 256, 0, stream>>>(E, cbh);
    k_main <<<2048, 256, 0, stream>>>(X, ETpk, cbh, E, out, counts, bsc);
    k_final<<<1, 256, 0, stream>>>(bsc, counts, out);
    hipMemcpyAsync(out + O_EMB, E, (size_t)4096 * 256 * sizeof(float),
                   hipMemcpyDeviceToDevice, stream);
}